// Round 17
// baseline (100.157 us; speedup 1.0000x reference)
//
#include <hip/hip_runtime.h>
#include <hip/hip_bf16.h>
#include <stdint.h>
#include <math.h>

typedef __bf16 bf16x8 __attribute__((ext_vector_type(8)));
typedef float f32x4 __attribute__((ext_vector_type(4)));
typedef float f32x16 __attribute__((ext_vector_type(16)));

#define B_    2
#define S_    2048
#define D_    1024
#define H_    16
#define HKV_  4
#define HD_   64
#define MTOT  4096      // B*S
#define NQKV  1536      // H*HD + 2*HKV*HD
#define BHS   65536     // B*H*S

#define ZERO16 {0.f,0.f,0.f,0.f,0.f,0.f,0.f,0.f,0.f,0.f,0.f,0.f,0.f,0.f,0.f,0.f}

__device__ __forceinline__ unsigned short f2bf(float f) {
  union { float f; unsigned u; } v; v.f = f;
  unsigned r = (v.u + 0x7FFFu + ((v.u >> 16) & 1u)) >> 16;
  return (unsigned short)r;
}

__device__ __forceinline__ float bf2f(unsigned short u) {
  union { unsigned u; float f; } v; v.u = (unsigned)u << 16; return v.f;
}

__device__ __forceinline__ float fast_exp2(float x) {
  return __builtin_amdgcn_exp2f(x);   // raw v_exp_f32 (1 instr, trans pipe)
}

__device__ __forceinline__ unsigned cvt_pk_bf16(float lo, float hi) {
  unsigned r;
  asm("v_cvt_pk_bf16_f32 %0, %1, %2" : "=v"(r) : "v"(lo), "v"(hi));
  return r;
}

__device__ __forceinline__ void gl_lds16(const void* g, void* l) {
  __builtin_amdgcn_global_load_lds((const __attribute__((address_space(1))) void*)g,
                                   (__attribute__((address_space(3))) void*)l, 16, 0, 0);
}

// ---------------- fused preprocessing: 4 weight transposes + rope tables + x->bf16 ----------------
__global__ __launch_bounds__(256) void k_pre(const float* __restrict__ Wq, const float* __restrict__ Wk,
                                             const float* __restrict__ Wv, const float* __restrict__ Wo,
                                             const float* __restrict__ x,
                                             unsigned short* __restrict__ wqkvt,
                                             unsigned short* __restrict__ wot,
                                             unsigned short* __restrict__ xb,
                                             float* __restrict__ cost, float* __restrict__ sint) {
  int bid = blockIdx.x, tid = threadIdx.x;
  if (bid < 640) {
    const float* src; unsigned short* dst; int ldsrc, cb, rb;
    if (bid < 256)      { src = Wq; dst = wqkvt;                          ldsrc = 1024; cb = (bid & 15) * 64; rb = (bid >> 4) * 64; }
    else if (bid < 320) { int i = bid - 256; src = Wk; dst = wqkvt + (size_t)1024 * 1024; ldsrc = 256; cb = (i & 3) * 64; rb = (i >> 2) * 64; }
    else if (bid < 384) { int i = bid - 320; src = Wv; dst = wqkvt + (size_t)1280 * 1024; ldsrc = 256; cb = (i & 3) * 64; rb = (i >> 2) * 64; }
    else                { int i = bid - 384; src = Wo; dst = wot;         ldsrc = 1024; cb = (i & 15) * 64; rb = (i >> 4) * 64; }
    __shared__ unsigned short T[64][72];
    for (int rep = 0; rep < 4; ++rep) {
      int idx = rep * 256 + tid;
      int r = idx >> 4, seg = idx & 15;
      float4 v = *(const float4*)&src[(size_t)(rb + r) * ldsrc + cb + seg * 4];
      T[seg*4+0][r] = f2bf(v.x);
      T[seg*4+1][r] = f2bf(v.y);
      T[seg*4+2][r] = f2bf(v.z);
      T[seg*4+3][r] = f2bf(v.w);
    }
    __syncthreads();
    for (int rep = 0; rep < 2; ++rep) {
      int idx = rep * 256 + tid;
      int c = idx >> 3, seg = idx & 7;
      *(uint4*)&dst[(size_t)(cb + c) * 1024 + rb + seg * 8] = *(const uint4*)&T[c][seg * 8];
    }
  } else if (bid < 896) {
    int idx = (bid - 640) * 256 + tid;
    int s = idx >> 5, i = idx & 31;
    double inv = exp(-(double)i / 32.0 * log(10000.0));
    double ang = (double)s * inv;
    cost[idx] = (float)cos(ang);
    sint[idx] = (float)sin(ang);
  } else {
    int i = (bid - 896) * 256 + tid;
    const int n4 = MTOT * D_ / 4;
    for (; i < n4; i += 1024 * 256) {
      float4 v = ((const float4*)x)[i];
      ushort4 o;
      o.x = f2bf(v.x); o.y = f2bf(v.y); o.z = f2bf(v.z); o.w = f2bf(v.w);
      ((ushort4*)xb)[i] = o;
    }
  }
}

// ---------------- QKV GEMM: BM=64 BN=128 BK=64, XOR-swizzled LDS, fused RoPE / V-transpose ----
__global__ __launch_bounds__(256) void k_gemm_qkv(const unsigned short* __restrict__ A,
                                                  const unsigned short* __restrict__ Bt,
                                                  const float* __restrict__ cost,
                                                  const float* __restrict__ sint,
                                                  unsigned short* __restrict__ Qb,
                                                  unsigned short* __restrict__ Kb,
                                                  unsigned short* __restrict__ Vt) {
  int nb = blockIdx.x, mb = blockIdx.y;     // nb: 0..11, mb: 0..63
  __shared__ unsigned short Arena[2][12288];  // per buf: A [64][64] (4096) | B [128][64] (8192)
  int tid = threadIdx.x, lane = tid & 63, w = tid >> 6;
  int wr = w >> 1, wc = w & 1;
  f32x4 acc[2][4];
  for (int m = 0; m < 2; ++m) for (int n = 0; n < 4; ++n) acc[m][n] = (f32x4){0.f, 0.f, 0.f, 0.f};

  const int rl = lane >> 3;
  const int csw = ((lane & 7) ^ rl) * 8;    // swizzled source chunk (elems)

  auto stage = [&](int buf, int kt) {
    for (int j = 0; j < 2; ++j)
      gl_lds16(&A[(size_t)(mb * 64 + w * 16 + j * 8 + rl) * D_ + kt * 64 + csw],
               &Arena[buf][(w * 16 + j * 8) * 64]);
    for (int j = 0; j < 4; ++j)
      gl_lds16(&Bt[(size_t)(nb * 128 + w * 32 + j * 8 + rl) * D_ + kt * 64 + csw],
               &Arena[buf][4096 + (w * 32 + j * 8) * 64]);
  };
  stage(0, 0);
  const int NT = D_ / 64;   // 16
  int cur = 0;
  const int lr = lane & 15, lg = lane >> 4, swl = lane & 7;
  for (int kt = 0; kt < NT; ++kt) {
    __syncthreads();
    if (kt + 1 < NT) stage(cur ^ 1, kt + 1);
    #pragma unroll
    for (int kk = 0; kk < 2; ++kk) {
      int ch = ((kk * 4 + lg) ^ swl) * 8;
      bf16x8 af[2], bfr[4];
      for (int m = 0; m < 2; ++m) af[m]  = *(const bf16x8*)&Arena[cur][(wr * 32 + m * 16 + lr) * 64 + ch];
      for (int n = 0; n < 4; ++n) bfr[n] = *(const bf16x8*)&Arena[cur][4096 + (wc * 64 + n * 16 + lr) * 64 + ch];
      for (int m = 0; m < 2; ++m)
        for (int n = 0; n < 4; ++n)
          acc[m][n] = __builtin_amdgcn_mfma_f32_16x16x32_bf16(af[m], bfr[n], acc[m][n], 0, 0, 0);
    }
    cur ^= 1;
  }

  const int lq = (lane >> 4) * 4;
  const int b = mb >> 5;
  const int s0 = (mb & 31) * 64;

  if (nb < 10) {
    const float QSCALE = 0.18033688011112042f;   // 0.125 * log2(e)
    float scl = (nb < 8) ? QSCALE : 1.f;
    #pragma unroll
    for (int m = 0; m < 2; ++m) {
      #pragma unroll
      for (int n = 0; n < 4; ++n) {
        int gc = nb * 128 + wc * 64 + n * 16 + lr;
        int d  = gc & 63, d2 = d & 31;
        float sgn = (d < 32) ? -1.f : 1.f;
        unsigned short* dst;
        if (nb < 8) {
          int h = gc >> 6;
          dst = Qb + (((size_t)(b * H_ + h)) * S_) * HD_ + d;
        } else {
          int hk = (gc - 1024) >> 6;
          dst = Kb + (((size_t)(b * HKV_ + hk)) * S_) * HD_ + d;
        }
        #pragma unroll
        for (int r = 0; r < 4; ++r) {
          int s = s0 + wr * 32 + m * 16 + lq + r;
          float c  = cost[s * 32 + d2];
          float sn = sint[s * 32 + d2];
          float xv = acc[m][n][r];
          float xp = acc[m][n ^ 2][r];
          float o = (xv * c + sgn * xp * sn) * scl;
          dst[(size_t)s * HD_] = f2bf(o);
        }
      }
    }
  } else {
    __syncthreads();
    unsigned short* T = &Arena[0][0];
    #pragma unroll
    for (int m = 0; m < 2; ++m)
      #pragma unroll
      for (int n = 0; n < 4; ++n)
        #pragma unroll
        for (int r = 0; r < 4; ++r) {
          int c = wc * 64 + n * 16 + lr;
          int rw = wr * 32 + m * 16 + lq + r;
          T[c * 72 + rw] = f2bf(acc[m][n][r]);
        }
    __syncthreads();
    {
      int j = tid >> 1, q = tid & 1;
      int v_off = (nb - 10) * 128 + j;
      int hk = v_off >> 6, dl = v_off & 63;
      unsigned short* dst = Vt + (((size_t)(b * HKV_ + hk)) * HD_ + dl) * S_ + s0 + q * 32;
      const unsigned short* srcp = &T[j * 72 + q * 32];
      #pragma unroll
      for (int k2 = 0; k2 < 4; ++k2)
        *(uint4*)&dst[k2 * 8] = *(const uint4*)&srcp[k2 * 8];
    }
  }
}

// ---------------- Wo GEMM: BM=64 BN=128 BK=64, split-K x2, XOR-swizzled LDS ----------------
__global__ __launch_bounds__(256) void k_gemm_bt(const unsigned short* __restrict__ A,
                                                 const unsigned short* __restrict__ Bt,
                                                 unsigned short* __restrict__ C0,
                                                 unsigned short* __restrict__ C1,
                                                 int M, int N, int Kfull) {
  int nb = blockIdx.x, mb = blockIdx.y, z = blockIdx.z;
  int kbase = z * (Kfull >> 1);
  int Klen = Kfull >> 1;
  unsigned short* C = z ? C1 : C0;
  __shared__ unsigned short Arena[2][12288];
  int tid = threadIdx.x, lane = tid & 63, w = tid >> 6;
  int wr = w >> 1, wc = w & 1;
  f32x4 acc[2][4];
  for (int m = 0; m < 2; ++m) for (int n = 0; n < 4; ++n) acc[m][n] = (f32x4){0.f, 0.f, 0.f, 0.f};

  const int rl = lane >> 3;
  const int csw = ((lane & 7) ^ rl) * 8;

  auto stage = [&](int buf, int kt) {
    for (int j = 0; j < 2; ++j)
      gl_lds16(&A[(size_t)(mb * 64 + w * 16 + j * 8 + rl) * Kfull + kbase + kt * 64 + csw],
               &Arena[buf][(w * 16 + j * 8) * 64]);
    for (int j = 0; j < 4; ++j)
      gl_lds16(&Bt[(size_t)(nb * 128 + w * 32 + j * 8 + rl) * Kfull + kbase + kt * 64 + csw],
               &Arena[buf][4096 + (w * 32 + j * 8) * 64]);
  };
  stage(0, 0);
  int NT = Klen / 64;   // 8
  int cur = 0;
  const int lr = lane & 15, lg = lane >> 4, swl = lane & 7;
  for (int kt = 0; kt < NT; ++kt) {
    __syncthreads();
    if (kt + 1 < NT) stage(cur ^ 1, kt + 1);
    #pragma unroll
    for (int kk = 0; kk < 2; ++kk) {
      int ch = ((kk * 4 + lg) ^ swl) * 8;
      bf16x8 af[2], bfr[4];
      for (int m = 0; m < 2; ++m) af[m]  = *(const bf16x8*)&Arena[cur][(wr * 32 + m * 16 + lr) * 64 + ch];
      for (int n = 0; n < 4; ++n) bfr[n] = *(const bf16x8*)&Arena[cur][4096 + (wc * 64 + n * 16 + lr) * 64 + ch];
      for (int m = 0; m < 2; ++m)
        for (int n = 0; n < 4; ++n)
          acc[m][n] = __builtin_amdgcn_mfma_f32_16x16x32_bf16(af[m], bfr[n], acc[m][n], 0, 0, 0);
    }
    cur ^= 1;
  }
  int lq = (lane >> 4) * 4;
  for (int m = 0; m < 2; ++m)
    for (int n = 0; n < 4; ++n)
      for (int r = 0; r < 4; ++r)
        C[(size_t)(mb * 64 + wr * 32 + m * 16 + lq + r) * N + nb * 128 + wc * 64 + n * 16 + lr] =
            f2bf(acc[m][n][r]);
}

// ---------------- flash attention v16: 1024-thread blocks, 4 kv-groups, single-buffer --------
// 16 waves = 4 groups x 4 waves; group g handles keys [g*512, (g+1)*512) in its own 16KB
// arena [K|V] (single-buffered: stage->sync->compute->sync). Grid 512 x 2 blocks/CU resident
// (LDS 64KB, regs ~60) -> 32 waves/CU = 8/SIMD: TLP attack on the latency plateau.
// Epilogue: groups 1..3 park bf16-packed O + l in LDS (52KB); group 0 combines and writes.
__global__ __launch_bounds__(1024, 2) void k_attn(const unsigned short* __restrict__ Q,
                                                  const unsigned short* __restrict__ K,
                                                  const unsigned short* __restrict__ Vt,
                                                  unsigned short* __restrict__ Ob) {
  int wg = ((blockIdx.x & 7) << 6) | (blockIdx.x >> 3);
  int qt = wg & 15;                   // 0..15
  int bh = wg >> 4;                   // 0..31
  int b = bh >> 4, h = bh & 15, hk = h >> 2;
  const unsigned short* Qp = Q + (((size_t)(b * H_ + h)) * S_ + qt * 128) * HD_;
  const unsigned short* Kp = K + ((size_t)(b * HKV_ + hk)) * S_ * HD_;     // [S][64]
  const unsigned short* Vp = Vt + ((size_t)(b * HKV_ + hk)) * HD_ * S_;    // [64][S]

  __shared__ unsigned short Lds[4 * 8192];    // group g: [K | V] x 4096 elems at g*8192 (64KB)

  const int tid = threadIdx.x, lane = tid & 63, w = tid >> 6;   // w: 0..15
  const int g  = w >> 2;              // kv quarter 0..3
  const int wl = w & 3;               // wave within group
  const int col = lane & 31;
  const int hi  = lane >> 5;
  const int sw  = lane & 7;
  const int kv0 = g * (S_ / 4);       // 512 keys per group
  const int gbase = g * 8192;

  const unsigned short* pka[4];
  #pragma unroll
  for (int kc = 0; kc < 4; ++kc)
    pka[kc] = &Lds[gbase + col * 64 + ((kc * 2 + hi) ^ sw) * 8];

  bf16x8 qf[4];
  {
    const unsigned short* qrow = Qp + (size_t)(wl * 32 + col) * HD_;
    #pragma unroll
    for (int dc = 0; dc < 4; ++dc)
      qf[dc] = *(const bf16x8*)&qrow[dc * 16 + hi * 8];
  }

  union { unsigned short s[8]; bf16x8 v; } onesu;
  #pragma unroll
  for (int i = 0; i < 8; ++i) onesu.s[i] = 0x3F80;
  const bf16x8 ones = onesu.v;

  f32x16 oacc0 = ZERO16, oacc1 = ZERO16, lacc = ZERO16;

  const int rl = lane >> 3, cs = lane & 7;
  const int row0 = wl * 16 + rl;
  const int csrc = (cs ^ (row0 & 7)) * 8;
  const unsigned short* srcK = &Kp[(size_t)(kv0 + row0) * HD_ + csrc];
  const unsigned short* srcV = &Vp[(size_t)row0 * S_ + kv0 + csrc];

  auto stage = [&]() {
    gl_lds16(srcK,           &Lds[gbase + (wl * 16) * 64]);
    gl_lds16(srcK + 8 * HD_, &Lds[gbase + (wl * 16 + 8) * 64]);
    gl_lds16(srcV,           &Lds[gbase + 4096 + (wl * 16) * 64]);
    gl_lds16(srcV + 8 * S_,  &Lds[gbase + 4096 + (wl * 16 + 8) * 64]);
    srcK += 64 * HD_;
    srcV += 64;
  };

  auto compute = [&]() {
    bf16x8 pf[4];
    #pragma unroll
    for (int blk2 = 0; blk2 < 2; ++blk2) {
      f32x16 st = ZERO16;
      __builtin_amdgcn_s_setprio(1);
      #pragma unroll
      for (int kc = 0; kc < 4; ++kc) {
        bf16x8 kf = *(const bf16x8*)(pka[kc] + blk2 * 2048);
        st = __builtin_amdgcn_mfma_f32_32x32x16_bf16(kf, qf[kc], st, 0, 0, 0);
      }
      __builtin_amdgcn_s_setprio(0);
      #pragma unroll
      for (int i = 0; i < 16; ++i)
        st[i] = fast_exp2(st[i]);
      #pragma unroll
      for (int kcl = 0; kcl < 2; ++kcl) {
        int base = kcl * 8;
        unsigned u0 = cvt_pk_bf16(st[base + 0], st[base + 1]);
        unsigned u1 = cvt_pk_bf16(st[base + 2], st[base + 3]);
        unsigned u2 = cvt_pk_bf16(st[base + 4], st[base + 5]);
        unsigned u3 = cvt_pk_bf16(st[base + 6], st[base + 7]);
        asm("v_permlane32_swap_b32 %0, %1" : "+v"(u0), "+v"(u2));
        asm("v_permlane32_swap_b32 %0, %1" : "+v"(u1), "+v"(u3));
        union { unsigned u[4]; bf16x8 v; } pk;
        pk.u[0] = u0; pk.u[1] = u1; pk.u[2] = u2; pk.u[3] = u3;
        pf[blk2 * 2 + kcl] = pk.v;
      }
    }
    __builtin_amdgcn_s_setprio(1);
    #pragma unroll
    for (int kc = 0; kc < 4; ++kc)
      lacc = __builtin_amdgcn_mfma_f32_32x32x16_bf16(ones, pf[kc], lacc, 0, 0, 0);
    #pragma unroll
    for (int kc = 0; kc < 4; ++kc) {
      bf16x8 v0 = *(const bf16x8*)(pka[kc] + 4096);
      bf16x8 v1 = *(const bf16x8*)(pka[kc] + 4096 + 2048);
      oacc0 = __builtin_amdgcn_mfma_f32_32x32x16_bf16(v0, pf[kc], oacc0, 0, 0, 0);
      oacc1 = __builtin_amdgcn_mfma_f32_32x32x16_bf16(v1, pf[kc], oacc1, 0, 0, 0);
    }
    __builtin_amdgcn_s_setprio(0);
  };

  // 8 tiles per group, single-buffered; cross-block overlap supplies latency hiding
  for (int t = 0; t < 8; ++t) {
    stage();
    __syncthreads();                  // tile staged (drains vmcnt)
    compute();
    __syncthreads();                  // reads done before restage
  }

  // ---- epilogue: 4-way in-LDS combine, bf16-packed (768 lanes x 17 dwords = 52KB) ----
  unsigned* xch = (unsigned*)Lds;
  if (g != 0) {
    unsigned* slot = xch + ((size_t)((g - 1) * 4 + wl) * 64 + lane) * 17;
    #pragma unroll
    for (int i = 0; i < 8; ++i) slot[i]     = cvt_pk_bf16(oacc0[2*i], oacc0[2*i+1]);
    #pragma unroll
    for (int i = 0; i < 8; ++i) slot[8 + i] = cvt_pk_bf16(oacc1[2*i], oacc1[2*i+1]);
    union { float f; unsigned u; } lu; lu.f = lacc[0];
    slot[16] = lu.u;
  }
  __syncthreads();
  if (g == 0) {
    float l_tot = lacc[0];
    float o0[16], o1[16];
    #pragma unroll
    for (int i = 0; i < 16; ++i) { o0[i] = oacc0[i]; o1[i] = oacc1[i]; }
    #pragma unroll
    for (int gg = 0; gg < 3; ++gg) {
      const unsigned* slot = xch + ((size_t)(gg * 4 + wl) * 64 + lane) * 17;
      #pragma unroll
      for (int i = 0; i < 8; ++i) {
        unsigned pa = slot[i], pb = slot[8 + i];
        o0[2*i]   += bf2f((unsigned short)(pa & 0xFFFF));
        o0[2*i+1] += bf2f((unsigned short)(pa >> 16));
        o1[2*i]   += bf2f((unsigned short)(pb & 0xFFFF));
        o1[2*i+1] += bf2f((unsigned short)(pb >> 16));
      }
      union { float f; unsigned u; } lu; lu.u = slot[16];
      l_tot += lu.f;
    }
    float rinv = 1.f / l_tot;
    int qrow = qt * 128 + wl * 32 + col;
    unsigned short* ob = Ob + ((size_t)(b * S_ + qrow)) * D_ + h * 64;
    #pragma unroll
    for (int rr = 0; rr < 4; ++rr) {
      ushort4 v0, v1;
      v0.x = f2bf(o0[rr*4+0] * rinv); v0.y = f2bf(o0[rr*4+1] * rinv);
      v0.z = f2bf(o0[rr*4+2] * rinv); v0.w = f2bf(o0[rr*4+3] * rinv);
      v1.x = f2bf(o1[rr*4+0] * rinv); v1.y = f2bf(o1[rr*4+1] * rinv);
      v1.z = f2bf(o1[rr*4+2] * rinv); v1.w = f2bf(o1[rr*4+3] * rinv);
      *(ushort4*)&ob[8 * rr + 4 * hi]      = v0;
      *(ushort4*)&ob[32 + 8 * rr + 4 * hi] = v1;
    }
  }
}

// ---------------- RMSNorm rows of 1024, two bf16 K-split partials in -> f32 out ----------------
__global__ __launch_bounds__(256) void k_rmsnorm(const unsigned short* __restrict__ in0,
                                                 const unsigned short* __restrict__ in1,
                                                 const float* __restrict__ wt,
                                                 float* __restrict__ out) {
  int row = blockIdx.x, tid = threadIdx.x;
  ushort4 u0 = *(const ushort4*)&in0[(size_t)row * D_ + tid * 4];
  ushort4 u1 = *(const ushort4*)&in1[(size_t)row * D_ + tid * 4];
  float x0 = bf2f(u0.x) + bf2f(u1.x);
  float x1 = bf2f(u0.y) + bf2f(u1.y);
  float x2 = bf2f(u0.z) + bf2f(u1.z);
  float x3 = bf2f(u0.w) + bf2f(u1.w);
  float ss = x0 * x0 + x1 * x1 + x2 * x2 + x3 * x3;
  for (int o = 32; o >= 1; o >>= 1) ss += __shfl_xor(ss, o);
  __shared__ float red[4];
  if ((tid & 63) == 0) red[tid >> 6] = ss;
  __syncthreads();
  float tot = red[0] + red[1] + red[2] + red[3];
  float rinv = 1.f / sqrtf(tot * (1.f / 1024.f) + 1e-6f);
  float4 wv = ((const float4*)wt)[tid];
  float4 o;
  o.x = x0 * rinv * wv.x;
  o.y = x1 * rinv * wv.y;
  o.z = x2 * rinv * wv.z;
  o.w = x3 * rinv * wv.w;
  ((float4*)(out + (size_t)row * D_))[tid] = o;
}

extern "C" void kernel_launch(void* const* d_in, const int* in_sizes, int n_in,
                              void* d_out, int out_size, void* d_ws, size_t ws_size,
                              hipStream_t stream) {
  const float* x  = (const float*)d_in[0];
  const float* Wq = (const float*)d_in[1];
  const float* Wk = (const float*)d_in[2];
  const float* Wv = (const float*)d_in[3];
  const float* Wo = (const float*)d_in[4];
  const float* nw = (const float*)d_in[5];
  float* out = (float*)d_out;

  char* p = (char*)d_ws;
  unsigned short* xb    = (unsigned short*)p; p += (size_t)MTOT * D_ * 2;        // 8.4 MB
  char*           slot  = p;                  p += (size_t)18 * 1024 * 1024;     // 18.9 MB multi-use
  unsigned short* wqkvt = (unsigned short*)p; p += (size_t)NQKV * D_ * 2;        // 3.1 MB
  unsigned short* wot   = (unsigned short*)p; p += (size_t)D_ * D_ * 2;          // 2.1 MB
  unsigned short* qb    = (unsigned short*)p; p += (size_t)B_ * H_ * S_ * HD_ * 2;   // 8.4 MB
  unsigned short* kb    = (unsigned short*)p; p += (size_t)B_ * HKV_ * S_ * HD_ * 2; // 2.1 MB
  unsigned short* vtb   = (unsigned short*)p; p += (size_t)B_ * HKV_ * HD_ * S_ * 2; // 2.1 MB
  char*           big2  = p;                  p += (size_t)MTOT * D_ * 2 * 2;    // 16.8 MB multi-use
  float*          mlold = (float*)p;          p += (size_t)2 * BHS * 4;
  float*          cost  = (float*)p;          p += (size_t)S_ * 32 * 4;
  float*          sint  = (float*)p;          p += (size_t)S_ * 32 * 4;
  (void)mlold;

  unsigned short* attnb   = (unsigned short*)big2;
  unsigned short* proj_p0 = (unsigned short*)slot;
  unsigned short* proj_p1 = (unsigned short*)(slot + (size_t)MTOT * D_ * 2);

  k_pre<<<1920, 256, 0, stream>>>(Wq, Wk, Wv, Wo, x, wqkvt, wot, xb, cost, sint);

  k_gemm_qkv<<<dim3(NQKV / 128, MTOT / 64), 256, 0, stream>>>(xb, wqkvt, cost, sint, qb, kb, vtb);
  k_attn<<<512, 1024, 0, stream>>>(qb, kb, vtb, attnb);
  k_gemm_bt<<<dim3(D_ / 128, MTOT / 64, 2), 256, 0, stream>>>(attnb, wot, proj_p0, proj_p1, MTOT, D_, D_);
  k_rmsnorm<<<MTOT, 256, 0, stream>>>(proj_p0, proj_p1, nw, out);
}

// Round 18
// 94.307 us; speedup vs baseline: 1.0620x; 1.0620x over previous
//
#include <hip/hip_runtime.h>
#include <hip/hip_bf16.h>
#include <stdint.h>
#include <math.h>

typedef __bf16 bf16x8 __attribute__((ext_vector_type(8)));
typedef float f32x4 __attribute__((ext_vector_type(4)));
typedef float f32x16 __attribute__((ext_vector_type(16)));

#define B_    2
#define S_    2048
#define D_    1024
#define H_    16
#define HKV_  4
#define HD_   64
#define MTOT  4096      // B*S
#define NQKV  1536      // H*HD + 2*HKV*HD
#define BHS   65536     // B*H*S

#define ZERO16 {0.f,0.f,0.f,0.f,0.f,0.f,0.f,0.f,0.f,0.f,0.f,0.f,0.f,0.f,0.f,0.f}

__device__ __forceinline__ unsigned short f2bf(float f) {
  union { float f; unsigned u; } v; v.f = f;
  unsigned r = (v.u + 0x7FFFu + ((v.u >> 16) & 1u)) >> 16;
  return (unsigned short)r;
}

__device__ __forceinline__ float bf2f(unsigned short u) {
  union { unsigned u; float f; } v; v.u = (unsigned)u << 16; return v.f;
}

__device__ __forceinline__ float fast_exp2(float x) {
  return __builtin_amdgcn_exp2f(x);   // raw v_exp_f32 (1 instr, trans pipe)
}

__device__ __forceinline__ unsigned cvt_pk_bf16(float lo, float hi) {
  unsigned r;
  asm("v_cvt_pk_bf16_f32 %0, %1, %2" : "=v"(r) : "v"(lo), "v"(hi));
  return r;
}

__device__ __forceinline__ void gl_lds16(const void* g, void* l) {
  __builtin_amdgcn_global_load_lds((const __attribute__((address_space(1))) void*)g,
                                   (__attribute__((address_space(3))) void*)l, 16, 0, 0);
}

// ---------------- fused preprocessing: 4 weight transposes + rope tables + x->bf16 ----------------
__global__ __launch_bounds__(256) void k_pre(const float* __restrict__ Wq, const float* __restrict__ Wk,
                                             const float* __restrict__ Wv, const float* __restrict__ Wo,
                                             const float* __restrict__ x,
                                             unsigned short* __restrict__ wqkvt,
                                             unsigned short* __restrict__ wot,
                                             unsigned short* __restrict__ xb,
                                             float* __restrict__ cost, float* __restrict__ sint) {
  int bid = blockIdx.x, tid = threadIdx.x;
  if (bid < 640) {
    const float* src; unsigned short* dst; int ldsrc, cb, rb;
    if (bid < 256)      { src = Wq; dst = wqkvt;                          ldsrc = 1024; cb = (bid & 15) * 64; rb = (bid >> 4) * 64; }
    else if (bid < 320) { int i = bid - 256; src = Wk; dst = wqkvt + (size_t)1024 * 1024; ldsrc = 256; cb = (i & 3) * 64; rb = (i >> 2) * 64; }
    else if (bid < 384) { int i = bid - 320; src = Wv; dst = wqkvt + (size_t)1280 * 1024; ldsrc = 256; cb = (i & 3) * 64; rb = (i >> 2) * 64; }
    else                { int i = bid - 384; src = Wo; dst = wot;         ldsrc = 1024; cb = (i & 15) * 64; rb = (i >> 4) * 64; }
    __shared__ unsigned short T[64][72];
    for (int rep = 0; rep < 4; ++rep) {
      int idx = rep * 256 + tid;
      int r = idx >> 4, seg = idx & 15;
      float4 v = *(const float4*)&src[(size_t)(rb + r) * ldsrc + cb + seg * 4];
      T[seg*4+0][r] = f2bf(v.x);
      T[seg*4+1][r] = f2bf(v.y);
      T[seg*4+2][r] = f2bf(v.z);
      T[seg*4+3][r] = f2bf(v.w);
    }
    __syncthreads();
    for (int rep = 0; rep < 2; ++rep) {
      int idx = rep * 256 + tid;
      int c = idx >> 3, seg = idx & 7;
      *(uint4*)&dst[(size_t)(cb + c) * 1024 + rb + seg * 8] = *(const uint4*)&T[c][seg * 8];
    }
  } else if (bid < 896) {
    int idx = (bid - 640) * 256 + tid;
    int s = idx >> 5, i = idx & 31;
    double inv = exp(-(double)i / 32.0 * log(10000.0));
    double ang = (double)s * inv;
    cost[idx] = (float)cos(ang);
    sint[idx] = (float)sin(ang);
  } else {
    int i = (bid - 896) * 256 + tid;
    const int n4 = MTOT * D_ / 4;
    for (; i < n4; i += 1024 * 256) {
      float4 v = ((const float4*)x)[i];
      ushort4 o;
      o.x = f2bf(v.x); o.y = f2bf(v.y); o.z = f2bf(v.z); o.w = f2bf(v.w);
      ((ushort4*)xb)[i] = o;
    }
  }
}

// ---------------- QKV GEMM: BM=64 BN=128 BK=64, XOR-swizzled LDS, fused RoPE / V-transpose ----
__global__ __launch_bounds__(256) void k_gemm_qkv(const unsigned short* __restrict__ A,
                                                  const unsigned short* __restrict__ Bt,
                                                  const float* __restrict__ cost,
                                                  const float* __restrict__ sint,
                                                  unsigned short* __restrict__ Qb,
                                                  unsigned short* __restrict__ Kb,
                                                  unsigned short* __restrict__ Vt) {
  int nb = blockIdx.x, mb = blockIdx.y;     // nb: 0..11, mb: 0..63
  __shared__ unsigned short Arena[2][12288];  // per buf: A [64][64] (4096) | B [128][64] (8192)
  int tid = threadIdx.x, lane = tid & 63, w = tid >> 6;
  int wr = w >> 1, wc = w & 1;
  f32x4 acc[2][4];
  for (int m = 0; m < 2; ++m) for (int n = 0; n < 4; ++n) acc[m][n] = (f32x4){0.f, 0.f, 0.f, 0.f};

  const int rl = lane >> 3;
  const int csw = ((lane & 7) ^ rl) * 8;    // swizzled source chunk (elems)

  auto stage = [&](int buf, int kt) {
    for (int j = 0; j < 2; ++j)
      gl_lds16(&A[(size_t)(mb * 64 + w * 16 + j * 8 + rl) * D_ + kt * 64 + csw],
               &Arena[buf][(w * 16 + j * 8) * 64]);
    for (int j = 0; j < 4; ++j)
      gl_lds16(&Bt[(size_t)(nb * 128 + w * 32 + j * 8 + rl) * D_ + kt * 64 + csw],
               &Arena[buf][4096 + (w * 32 + j * 8) * 64]);
  };
  stage(0, 0);
  const int NT = D_ / 64;   // 16
  int cur = 0;
  const int lr = lane & 15, lg = lane >> 4, swl = lane & 7;
  for (int kt = 0; kt < NT; ++kt) {
    __syncthreads();
    if (kt + 1 < NT) stage(cur ^ 1, kt + 1);
    #pragma unroll
    for (int kk = 0; kk < 2; ++kk) {
      int ch = ((kk * 4 + lg) ^ swl) * 8;
      bf16x8 af[2], bfr[4];
      for (int m = 0; m < 2; ++m) af[m]  = *(const bf16x8*)&Arena[cur][(wr * 32 + m * 16 + lr) * 64 + ch];
      for (int n = 0; n < 4; ++n) bfr[n] = *(const bf16x8*)&Arena[cur][4096 + (wc * 64 + n * 16 + lr) * 64 + ch];
      for (int m = 0; m < 2; ++m)
        for (int n = 0; n < 4; ++n)
          acc[m][n] = __builtin_amdgcn_mfma_f32_16x16x32_bf16(af[m], bfr[n], acc[m][n], 0, 0, 0);
    }
    cur ^= 1;
  }

  const int lq = (lane >> 4) * 4;
  const int b = mb >> 5;
  const int s0 = (mb & 31) * 64;

  if (nb < 10) {
    const float QSCALE = 0.18033688011112042f;   // 0.125 * log2(e)
    float scl = (nb < 8) ? QSCALE : 1.f;
    #pragma unroll
    for (int m = 0; m < 2; ++m) {
      #pragma unroll
      for (int n = 0; n < 4; ++n) {
        int gc = nb * 128 + wc * 64 + n * 16 + lr;
        int d  = gc & 63, d2 = d & 31;
        float sgn = (d < 32) ? -1.f : 1.f;
        unsigned short* dst;
        if (nb < 8) {
          int h = gc >> 6;
          dst = Qb + (((size_t)(b * H_ + h)) * S_) * HD_ + d;
        } else {
          int hk = (gc - 1024) >> 6;
          dst = Kb + (((size_t)(b * HKV_ + hk)) * S_) * HD_ + d;
        }
        #pragma unroll
        for (int r = 0; r < 4; ++r) {
          int s = s0 + wr * 32 + m * 16 + lq + r;
          float c  = cost[s * 32 + d2];
          float sn = sint[s * 32 + d2];
          float xv = acc[m][n][r];
          float xp = acc[m][n ^ 2][r];
          float o = (xv * c + sgn * xp * sn) * scl;
          dst[(size_t)s * HD_] = f2bf(o);
        }
      }
    }
  } else {
    __syncthreads();
    unsigned short* T = &Arena[0][0];
    #pragma unroll
    for (int m = 0; m < 2; ++m)
      #pragma unroll
      for (int n = 0; n < 4; ++n)
        #pragma unroll
        for (int r = 0; r < 4; ++r) {
          int c = wc * 64 + n * 16 + lr;
          int rw = wr * 32 + m * 16 + lq + r;
          T[c * 72 + rw] = f2bf(acc[m][n][r]);
        }
    __syncthreads();
    {
      int j = tid >> 1, q = tid & 1;
      int v_off = (nb - 10) * 128 + j;
      int hk = v_off >> 6, dl = v_off & 63;
      unsigned short* dst = Vt + (((size_t)(b * HKV_ + hk)) * HD_ + dl) * S_ + s0 + q * 32;
      const unsigned short* srcp = &T[j * 72 + q * 32];
      #pragma unroll
      for (int k2 = 0; k2 < 4; ++k2)
        *(uint4*)&dst[k2 * 8] = *(const uint4*)&srcp[k2 * 8];
    }
  }
}

// ---------------- Wo GEMM: BM=64 BN=128 BK=64, split-K x2, XOR-swizzled LDS ----------------
__global__ __launch_bounds__(256) void k_gemm_bt(const unsigned short* __restrict__ A,
                                                 const unsigned short* __restrict__ Bt,
                                                 unsigned short* __restrict__ C0,
                                                 unsigned short* __restrict__ C1,
                                                 int M, int N, int Kfull) {
  int nb = blockIdx.x, mb = blockIdx.y, z = blockIdx.z;
  int kbase = z * (Kfull >> 1);
  int Klen = Kfull >> 1;
  unsigned short* C = z ? C1 : C0;
  __shared__ unsigned short Arena[2][12288];
  int tid = threadIdx.x, lane = tid & 63, w = tid >> 6;
  int wr = w >> 1, wc = w & 1;
  f32x4 acc[2][4];
  for (int m = 0; m < 2; ++m) for (int n = 0; n < 4; ++n) acc[m][n] = (f32x4){0.f, 0.f, 0.f, 0.f};

  const int rl = lane >> 3;
  const int csw = ((lane & 7) ^ rl) * 8;

  auto stage = [&](int buf, int kt) {
    for (int j = 0; j < 2; ++j)
      gl_lds16(&A[(size_t)(mb * 64 + w * 16 + j * 8 + rl) * Kfull + kbase + kt * 64 + csw],
               &Arena[buf][(w * 16 + j * 8) * 64]);
    for (int j = 0; j < 4; ++j)
      gl_lds16(&Bt[(size_t)(nb * 128 + w * 32 + j * 8 + rl) * Kfull + kbase + kt * 64 + csw],
               &Arena[buf][4096 + (w * 32 + j * 8) * 64]);
  };
  stage(0, 0);
  int NT = Klen / 64;   // 8
  int cur = 0;
  const int lr = lane & 15, lg = lane >> 4, swl = lane & 7;
  for (int kt = 0; kt < NT; ++kt) {
    __syncthreads();
    if (kt + 1 < NT) stage(cur ^ 1, kt + 1);
    #pragma unroll
    for (int kk = 0; kk < 2; ++kk) {
      int ch = ((kk * 4 + lg) ^ swl) * 8;
      bf16x8 af[2], bfr[4];
      for (int m = 0; m < 2; ++m) af[m]  = *(const bf16x8*)&Arena[cur][(wr * 32 + m * 16 + lr) * 64 + ch];
      for (int n = 0; n < 4; ++n) bfr[n] = *(const bf16x8*)&Arena[cur][4096 + (wc * 64 + n * 16 + lr) * 64 + ch];
      for (int m = 0; m < 2; ++m)
        for (int n = 0; n < 4; ++n)
          acc[m][n] = __builtin_amdgcn_mfma_f32_16x16x32_bf16(af[m], bfr[n], acc[m][n], 0, 0, 0);
    }
    cur ^= 1;
  }
  int lq = (lane >> 4) * 4;
  for (int m = 0; m < 2; ++m)
    for (int n = 0; n < 4; ++n)
      for (int r = 0; r < 4; ++r)
        C[(size_t)(mb * 64 + wr * 32 + m * 16 + lq + r) * N + nb * 128 + wc * 64 + n * 16 + lr] =
            f2bf(acc[m][n][r]);
}

// ---------------- flash attention (best config): double-buffer 64KB, l-via-MFMA, XCD swizzle --
__global__ __launch_bounds__(512, 2) void k_attn(const unsigned short* __restrict__ Q,
                                                 const unsigned short* __restrict__ K,
                                                 const unsigned short* __restrict__ Vt,
                                                 unsigned short* __restrict__ Ob) {
  int wg = ((blockIdx.x & 7) << 6) | (blockIdx.x >> 3);
  int qt = wg & 15;                   // 0..15
  int bh = wg >> 4;                   // 0..31
  int b = bh >> 4, h = bh & 15, hk = h >> 2;
  const unsigned short* Qp = Q + (((size_t)(b * H_ + h)) * S_ + qt * 128) * HD_;
  const unsigned short* Kp = K + ((size_t)(b * HKV_ + hk)) * S_ * HD_;     // [S][64]
  const unsigned short* Vp = Vt + ((size_t)(b * HKV_ + hk)) * HD_ * S_;    // [64][S]

  __shared__ unsigned short Lds[2 * 16384];   // half g: [K0|K1|V0|V1] x 4096 elems at g*16384

  const int tid = threadIdx.x, lane = tid & 63, w = tid >> 6;   // w: 0..7
  const int g  = w >> 2;
  const int wl = w & 3;
  const int col = lane & 31;
  const int hi  = lane >> 5;
  const int sw  = lane & 7;
  const int kv0 = g * (S_ / 2);
  const int gbase = g * 16384;

  const unsigned short* pka[4];
  #pragma unroll
  for (int kc = 0; kc < 4; ++kc)
    pka[kc] = &Lds[gbase + col * 64 + ((kc * 2 + hi) ^ sw) * 8];

  bf16x8 qf[4];
  {
    const unsigned short* qrow = Qp + (size_t)(wl * 32 + col) * HD_;
    #pragma unroll
    for (int dc = 0; dc < 4; ++dc)
      qf[dc] = *(const bf16x8*)&qrow[dc * 16 + hi * 8];
  }

  union { unsigned short s[8]; bf16x8 v; } onesu;
  #pragma unroll
  for (int i = 0; i < 8; ++i) onesu.s[i] = 0x3F80;
  const bf16x8 ones = onesu.v;

  f32x16 oacc0 = ZERO16, oacc1 = ZERO16, lacc = ZERO16;

  const int rl = lane >> 3, cs = lane & 7;
  const int row0 = wl * 16 + rl;
  const int csrc = (cs ^ (row0 & 7)) * 8;
  const unsigned short* srcK = &Kp[(size_t)(kv0 + row0) * HD_ + csrc];
  const unsigned short* srcV = &Vp[(size_t)row0 * S_ + kv0 + csrc];

  auto stage = [&](int be) {                    // be in {0,4096}, literal at call
    gl_lds16(srcK,           &Lds[gbase + be + (wl * 16) * 64]);
    gl_lds16(srcK + 8 * HD_, &Lds[gbase + be + (wl * 16 + 8) * 64]);
    gl_lds16(srcV,           &Lds[gbase + be + 8192 + (wl * 16) * 64]);
    gl_lds16(srcV + 8 * S_,  &Lds[gbase + be + 8192 + (wl * 16 + 8) * 64]);
    srcK += 64 * HD_;
    srcV += 64;
  };

  auto compute = [&](int be) {                  // be in {0,4096}, literal at call
    bf16x8 pf[4];
    #pragma unroll
    for (int blk2 = 0; blk2 < 2; ++blk2) {
      f32x16 st = ZERO16;
      __builtin_amdgcn_s_setprio(1);
      #pragma unroll
      for (int kc = 0; kc < 4; ++kc) {
        bf16x8 kf = *(const bf16x8*)(pka[kc] + be + blk2 * 2048);
        st = __builtin_amdgcn_mfma_f32_32x32x16_bf16(kf, qf[kc], st, 0, 0, 0);
      }
      __builtin_amdgcn_s_setprio(0);
      #pragma unroll
      for (int i = 0; i < 16; ++i)
        st[i] = fast_exp2(st[i]);
      #pragma unroll
      for (int kcl = 0; kcl < 2; ++kcl) {
        int base = kcl * 8;
        unsigned u0 = cvt_pk_bf16(st[base + 0], st[base + 1]);
        unsigned u1 = cvt_pk_bf16(st[base + 2], st[base + 3]);
        unsigned u2 = cvt_pk_bf16(st[base + 4], st[base + 5]);
        unsigned u3 = cvt_pk_bf16(st[base + 6], st[base + 7]);
        asm("v_permlane32_swap_b32 %0, %1" : "+v"(u0), "+v"(u2));
        asm("v_permlane32_swap_b32 %0, %1" : "+v"(u1), "+v"(u3));
        union { unsigned u[4]; bf16x8 v; } pk;
        pk.u[0] = u0; pk.u[1] = u1; pk.u[2] = u2; pk.u[3] = u3;
        pf[blk2 * 2 + kcl] = pk.v;
      }
    }
    __builtin_amdgcn_s_setprio(1);
    #pragma unroll
    for (int kc = 0; kc < 4; ++kc)
      lacc = __builtin_amdgcn_mfma_f32_32x32x16_bf16(ones, pf[kc], lacc, 0, 0, 0);
    #pragma unroll
    for (int kc = 0; kc < 4; ++kc) {
      bf16x8 v0 = *(const bf16x8*)(pka[kc] + be + 8192);
      bf16x8 v1 = *(const bf16x8*)(pka[kc] + be + 8192 + 2048);
      oacc0 = __builtin_amdgcn_mfma_f32_32x32x16_bf16(v0, pf[kc], oacc0, 0, 0, 0);
      oacc1 = __builtin_amdgcn_mfma_f32_32x32x16_bf16(v1, pf[kc], oacc1, 0, 0, 0);
    }
    __builtin_amdgcn_s_setprio(0);
  };

  // NT = 16 tiles per half: tile t -> buffer (t%2)
  stage(0);
  for (int it = 0; it < 8; ++it) {
    __syncthreads();                  // tile 2it staged
    stage(4096);                      // tile 2it+1 in flight over compute
    compute(0);
    __syncthreads();                  // tile 2it+1 staged; buf0 reads done
    if (it < 7) stage(0);             // tile 2it+2
    compute(4096);
  }

  // ---- epilogue: in-LDS split combine ----
  __syncthreads();
  float* xch = (float*)Lds;           // 4 waves x 64 lanes x 33 f32
  if (g == 0) {
    float* slot = xch + ((size_t)wl * 64 + lane) * 33;
    #pragma unroll
    for (int i = 0; i < 16; ++i) { slot[i] = oacc0[i]; slot[16 + i] = oacc1[i]; }
    slot[32] = lacc[0];
  }
  __syncthreads();
  if (g == 1) {
    const float* slot = xch + ((size_t)wl * 64 + lane) * 33;
    float rinv = 1.f / (lacc[0] + slot[32]);
    int qrow = qt * 128 + wl * 32 + col;
    unsigned short* ob = Ob + ((size_t)(b * S_ + qrow)) * D_ + h * 64;
    #pragma unroll
    for (int rr = 0; rr < 4; ++rr) {
      ushort4 o0, o1;
      o0.x = f2bf((oacc0[rr*4+0] + slot[rr*4+0]) * rinv);
      o0.y = f2bf((oacc0[rr*4+1] + slot[rr*4+1]) * rinv);
      o0.z = f2bf((oacc0[rr*4+2] + slot[rr*4+2]) * rinv);
      o0.w = f2bf((oacc0[rr*4+3] + slot[rr*4+3]) * rinv);
      o1.x = f2bf((oacc1[rr*4+0] + slot[16+rr*4+0]) * rinv);
      o1.y = f2bf((oacc1[rr*4+1] + slot[16+rr*4+1]) * rinv);
      o1.z = f2bf((oacc1[rr*4+2] + slot[16+rr*4+2]) * rinv);
      o1.w = f2bf((oacc1[rr*4+3] + slot[16+rr*4+3]) * rinv);
      *(ushort4*)&ob[8 * rr + 4 * hi]      = o0;
      *(ushort4*)&ob[32 + 8 * rr + 4 * hi] = o1;
    }
  }
}

// ---------------- RMSNorm rows of 1024, two bf16 K-split partials in -> f32 out ----------------
__global__ __launch_bounds__(256) void k_rmsnorm(const unsigned short* __restrict__ in0,
                                                 const unsigned short* __restrict__ in1,
                                                 const float* __restrict__ wt,
                                                 float* __restrict__ out) {
  int row = blockIdx.x, tid = threadIdx.x;
  ushort4 u0 = *(const ushort4*)&in0[(size_t)row * D_ + tid * 4];
  ushort4 u1 = *(const ushort4*)&in1[(size_t)row * D_ + tid * 4];
  float x0 = bf2f(u0.x) + bf2f(u1.x);
  float x1 = bf2f(u0.y) + bf2f(u1.y);
  float x2 = bf2f(u0.z) + bf2f(u1.z);
  float x3 = bf2f(u0.w) + bf2f(u1.w);
  float ss = x0 * x0 + x1 * x1 + x2 * x2 + x3 * x3;
  for (int o = 32; o >= 1; o >>= 1) ss += __shfl_xor(ss, o);
  __shared__ float red[4];
  if ((tid & 63) == 0) red[tid >> 6] = ss;
  __syncthreads();
  float tot = red[0] + red[1] + red[2] + red[3];
  float rinv = 1.f / sqrtf(tot * (1.f / 1024.f) + 1e-6f);
  float4 wv = ((const float4*)wt)[tid];
  float4 o;
  o.x = x0 * rinv * wv.x;
  o.y = x1 * rinv * wv.y;
  o.z = x2 * rinv * wv.z;
  o.w = x3 * rinv * wv.w;
  ((float4*)(out + (size_t)row * D_))[tid] = o;
}

extern "C" void kernel_launch(void* const* d_in, const int* in_sizes, int n_in,
                              void* d_out, int out_size, void* d_ws, size_t ws_size,
                              hipStream_t stream) {
  const float* x  = (const float*)d_in[0];
  const float* Wq = (const float*)d_in[1];
  const float* Wk = (const float*)d_in[2];
  const float* Wv = (const float*)d_in[3];
  const float* Wo = (const float*)d_in[4];
  const float* nw = (const float*)d_in[5];
  float* out = (float*)d_out;

  char* p = (char*)d_ws;
  unsigned short* xb    = (unsigned short*)p; p += (size_t)MTOT * D_ * 2;        // 8.4 MB
  char*           slot  = p;                  p += (size_t)18 * 1024 * 1024;     // 18.9 MB multi-use
  unsigned short* wqkvt = (unsigned short*)p; p += (size_t)NQKV * D_ * 2;        // 3.1 MB
  unsigned short* wot   = (unsigned short*)p; p += (size_t)D_ * D_ * 2;          // 2.1 MB
  unsigned short* qb    = (unsigned short*)p; p += (size_t)B_ * H_ * S_ * HD_ * 2;   // 8.4 MB
  unsigned short* kb    = (unsigned short*)p; p += (size_t)B_ * HKV_ * S_ * HD_ * 2; // 2.1 MB
  unsigned short* vtb   = (unsigned short*)p; p += (size_t)B_ * HKV_ * HD_ * S_ * 2; // 2.1 MB
  char*           big2  = p;                  p += (size_t)MTOT * D_ * 2 * 2;    // 16.8 MB multi-use
  float*          mlold = (float*)p;          p += (size_t)2 * BHS * 4;
  float*          cost  = (float*)p;          p += (size_t)S_ * 32 * 4;
  float*          sint  = (float*)p;          p += (size_t)S_ * 32 * 4;
  (void)mlold;

  unsigned short* attnb   = (unsigned short*)big2;
  unsigned short* proj_p0 = (unsigned short*)slot;
  unsigned short* proj_p1 = (unsigned short*)(slot + (size_t)MTOT * D_ * 2);

  k_pre<<<1920, 256, 0, stream>>>(Wq, Wk, Wv, Wo, x, wqkvt, wot, xb, cost, sint);

  k_gemm_qkv<<<dim3(NQKV / 128, MTOT / 64), 256, 0, stream>>>(xb, wqkvt, cost, sint, qb, kb, vtb);
  k_attn<<<512, 512, 0, stream>>>(qb, kb, vtb, attnb);
  k_gemm_bt<<<dim3(D_ / 128, MTOT / 64, 2), 256, 0, stream>>>(attnb, wot, proj_p0, proj_p1, MTOT, D_, D_);
  k_rmsnorm<<<MTOT, 256, 0, stream>>>(proj_p0, proj_p1, nw, out);
}